// Round 3
// baseline (1562.805 us; speedup 1.0000x reference)
//
#include <hip/hip_runtime.h>
#include <cmath>
#include <cstddef>
#include <cstdint>

// ---------------------------------------------------------------------------
// Round 5: 8-phase-style deep-pipelined GEMM (T2+T3+T4+T5 per the guide).
// R4 hit the m97-structure ceiling (gemm6 = 833 TF, MfmaUtil 38%): the
// per-K-step vmcnt(0) drain at __syncthreads is structural. New gemm8p:
// BN=256, BK=64, 512 thr / 8 waves (2Mx4N), double-buffered XOR-swizzled
// LDS, counted s_waitcnt vmcnt(N) once per K-tile (never 0 in-loop), raw
// s_barrier phase-locking, setprio(1) around MFMA clusters. BM=256 for
// gemm6 (256 blocks), BM=128 for the M=2048 GEMMs. gemm5a+5b fused into
// one [2048x8192] GEMM (wmh/wlh adjacent). Old 128^2 kernel kept for
// gemm2 (N=2048) and gemm7 (N=1024).
// ---------------------------------------------------------------------------

typedef _Float16 f16x8 __attribute__((ext_vector_type(8)));
typedef _Float16 f16x4 __attribute__((ext_vector_type(4)));
typedef float    f32x16 __attribute__((ext_vector_type(16)));

__device__ __forceinline__ void load_lds16(const _Float16* g, _Float16* l)
{
    __builtin_amdgcn_global_load_lds(
        (const __attribute__((address_space(1))) void*)g,
        (__attribute__((address_space(3))) void*)l, 16, 0, 0);
}

__device__ __forceinline__ void bar()
{
    asm volatile("" ::: "memory");
    __builtin_amdgcn_s_barrier();
    asm volatile("" ::: "memory");
}

// Stable binary argsort of mask (mm%2): perm = [evens..., odds...].
__global__ __launch_bounds__(1024)
void perm_kernel(const int* __restrict__ mm, int* __restrict__ perm)
{
    __shared__ int sdata[1024];
    const int t = threadIdx.x;
    int m[4]; int cnt = 0;
#pragma unroll
    for (int j = 0; j < 4; ++j) { int i = t*4 + j; m[j] = mm[i] & 1; cnt += m[j]; }
    sdata[t] = cnt;
    __syncthreads();
    for (int off = 1; off < 1024; off <<= 1) {
        int v = (t >= off) ? sdata[t - off] : 0;
        __syncthreads();
        sdata[t] += v;
        __syncthreads();
    }
    const int n0 = 4096 - sdata[1023];
    int ones_before  = sdata[t] - cnt;
    int zeros_before = t*4 - ones_before;
#pragma unroll
    for (int j = 0; j < 4; ++j) {
        int i = t*4 + j;
        if (m[j]) perm[n0 + (ones_before++)] = i;
        else      perm[(zeros_before++)]     = i;
    }
}

// x fp32 -> comb16 top half (unmasked rows) and xm16 (masked rows), fp16.
__global__ __launch_bounds__(256)
void gather_kernel(const float* __restrict__ x, const int* __restrict__ perm,
                   _Float16* __restrict__ comb, _Float16* __restrict__ xm)
{
    const int p  = blockIdx.y;
    const int c4 = blockIdx.x * 256 + threadIdx.x;   // float4 col 0..1023
    const int src = perm[p];
    const float4 v = *(const float4*)(x + (size_t)src * 4096 + (size_t)c4 * 4);
    f16x4 h = { (_Float16)v.x, (_Float16)v.y, (_Float16)v.z, (_Float16)v.w };
    if (p < 2048) *(f16x4*)(comb + (size_t)p * 4096 + (size_t)c4 * 4) = h;
    else          *(f16x4*)(xm + (size_t)(p - 2048) * 4096 + (size_t)c4 * 4) = h;
}

// All six flat weight matrices fp32 -> fp16 in one launch (22M float4).
__global__ __launch_bounds__(256)
void cvt_all_kernel(const float* __restrict__ Wr1, const float* __restrict__ Wlv,
                    const float* __restrict__ Wg1, const float* __restrict__ Wm,
                    const float* __restrict__ Wl,  const float* __restrict__ W1,
                    _Float16* __restrict__ wr1h, _Float16* __restrict__ wlvh,
                    _Float16* __restrict__ wg1h, _Float16* __restrict__ wmh,
                    _Float16* __restrict__ wlh,  _Float16* __restrict__ w1h)
{
    int i = blockIdx.x * 256 + threadIdx.x;          // float4 index
    const float* s; _Float16* d; int off;
    if      (i <  4194304) { s = Wr1; d = wr1h; off = 0; }
    else if (i <  6291456) { s = Wlv; d = wlvh; off =  4194304; }
    else if (i < 10485760) { s = Wg1; d = wg1h; off =  6291456; }
    else if (i < 14680064) { s = Wm;  d = wmh;  off = 10485760; }
    else if (i < 18874368) { s = Wl;  d = wlh;  off = 14680064; }
    else                   { s = W1;  d = w1h;  off = 18874368; }
    int j = i - off;
    float4 v = ((const float4*)s)[j];
    f16x4 h = { (_Float16)v.x, (_Float16)v.y, (_Float16)v.z, (_Float16)v.w };
    ((f16x4*)d)[j] = h;
}

// W2 [1000,4096] fp32 -> [1024,4096] fp16, rows 1000..1023 zeroed.
__global__ __launch_bounds__(256)
void cvt_w2_kernel(const float* __restrict__ src, _Float16* __restrict__ dst)
{
    int i = blockIdx.x * 256 + threadIdx.x;      // float4 index, 1M total
    int row = (i * 4) >> 12;
    f16x4 h = { (_Float16)0.f, (_Float16)0.f, (_Float16)0.f, (_Float16)0.f };
    if (row < 1000) {
        float4 v = ((const float4*)src)[i];
        h = f16x4{ (_Float16)v.x, (_Float16)v.y, (_Float16)v.z, (_Float16)v.w };
    }
    ((f16x4*)dst)[i] = h;
}

// priors [2048,4096] fp32 -> priorsT [4096,2048] fp16 (tiled transpose).
__global__ __launch_bounds__(256)
void cvt_t_kernel(const float* __restrict__ src, _Float16* __restrict__ dst)
{
    __shared__ float t[32][33];
    const int tx = threadIdx.x, ty = threadIdx.y;
    const int c0 = blockIdx.x * 32, r0 = blockIdx.y * 32;
#pragma unroll
    for (int j = 0; j < 4; ++j)
        t[ty + 8*j][tx] = src[(size_t)(r0 + ty + 8*j) * 4096 + c0 + tx];
    __syncthreads();
#pragma unroll
    for (int j = 0; j < 4; ++j)
        dst[(size_t)(c0 + ty + 8*j) * 2048 + r0 + tx] = (_Float16)t[tx][ty + 8*j];
}

// ---------------------------------------------------------------------------
// Streaming VAE elementwise kernels.
// ---------------------------------------------------------------------------

// w = 1 + sqrt(exp(lv)) * eps_w[g];  lv fp32 [2048,2048].
__global__ __launch_bounds__(256)
void ew_w_kernel(const float* __restrict__ lv, const float* __restrict__ eps_w,
                 const int* __restrict__ perm, _Float16* __restrict__ w16,
                 float* __restrict__ out_w, float* __restrict__ out_var)
{
    const int r  = blockIdx.x;                 // 0..2047
    const int g  = perm[2048 + r];             // original row index
    const int c0 = threadIdx.x * 8;            // 256 threads * 8 = 2048 cols
    const size_t ro = (size_t)r * 2048 + c0;
    const size_t go = (size_t)g * 2048 + c0;
    float4 l0 = *(const float4*)(lv + ro);
    float4 l1 = *(const float4*)(lv + ro + 4);
    float4 e0 = *(const float4*)(eps_w + go);
    float4 e1 = *(const float4*)(eps_w + go + 4);
    float lvv[8] = { l0.x, l0.y, l0.z, l0.w, l1.x, l1.y, l1.z, l1.w };
    float ev[8]  = { e0.x, e0.y, e0.z, e0.w, e1.x, e1.y, e1.z, e1.w };
    float wv[8], vv[8];
    f16x8 wh;
#pragma unroll
    for (int j = 0; j < 8; ++j) {
        vv[j] = __expf(lvv[j]);
        wv[j] = fmaf(sqrtf(vv[j]), ev[j], 1.f);
        wh[j] = (_Float16)wv[j];
    }
    *(f16x8*)(w16 + ro) = wh;
    *(float4*)(out_w + ro)       = make_float4(wv[0], wv[1], wv[2], wv[3]);
    *(float4*)(out_w + ro + 4)   = make_float4(wv[4], wv[5], wv[6], wv[7]);
    *(float4*)(out_var + ro)     = make_float4(vv[0], vv[1], vv[2], vv[3]);
    *(float4*)(out_var + ro + 4) = make_float4(vv[4], vv[5], vv[6], vv[7]);
}

// In-place on comb16 bottom half: lr(fp16) -> x_rec * softplus(mean + exp(0.5*lr)*eps_r[g]).
__global__ __launch_bounds__(512)
void ew_reg_kernel(_Float16* __restrict__ comb_bot,
                   const _Float16* __restrict__ mean,
                   const _Float16* __restrict__ xrec,
                   const float* __restrict__ eps_r,
                   const int* __restrict__ perm)
{
    const int r  = blockIdx.x;                 // 0..2047
    const int g  = perm[2048 + r];
    const int c0 = threadIdx.x * 8;            // 512 threads * 8 = 4096 cols
    const size_t ro = (size_t)r * 4096 + c0;
    const size_t go = (size_t)g * 4096 + c0;
    f16x8 lr = *(const f16x8*)(comb_bot + ro);
    f16x8 mn = *(const f16x8*)(mean + ro);
    f16x8 xr = *(const f16x8*)(xrec + ro);
    float4 e0 = *(const float4*)(eps_r + go);
    float4 e1 = *(const float4*)(eps_r + go + 4);
    float ev[8] = { e0.x, e0.y, e0.z, e0.w, e1.x, e1.y, e1.z, e1.w };
    f16x8 ov;
#pragma unroll
    for (int j = 0; j < 8; ++j) {
        float sd = __expf(0.5f * (float)lr[j]);
        float z  = fmaf(sd, ev[j], (float)mn[j]);
        float sp = fmaxf(z, 0.f) + __logf(1.f + __expf(-fabsf(z)));
        ov[j] = (_Float16)((float)xr[j] * sp);
    }
    *(f16x8*)(comb_bot + ro) = ov;
}

// ---------------------------------------------------------------------------
// Deep-pipelined GEMM: C = A[M,K] @ B[N,K]^T. BN=256, BK=64, 512 thr =
// 8 waves (2M x 4N); wave tile (BM/2)x64 = MF x 2 of 32x32x16 MFMA.
// Double-buffered swizzled LDS; per K-tile, MF phases each issuing SPP
// global_load_lds for the NEXT buffer; single counted vmcnt per tile
// (vmcnt(SPP), never 0 in-loop); raw s_barrier per phase; setprio around
// the MFMA cluster. Swizzle: 16B chunk slot cc holds logical chunk
// c = cc ^ (r&7); staging pre-swizzles the GLOBAL source (dest linear).
// EPI: 0 ->C16; 1 relu+bias->C16; 4 split: cols<N/2 ->C16 (+bias),
// cols>=N/2 ->C2 (+bias2), both stride N/2.
// ---------------------------------------------------------------------------
template <int BM, int EPI>
__global__ __launch_bounds__(512, 2)
void gemm8p(const _Float16* __restrict__ A, const _Float16* __restrict__ B,
            _Float16* __restrict__ C16, _Float16* __restrict__ C2,
            int N, int K,
            const float* __restrict__ bias, const float* __restrict__ bias2)
{
    constexpr int MF  = BM / 64;        // M-frags per wave == A stage iters (4 or 2)
    constexpr int SPP = (MF + 4) / MF;  // stage issues per phase (2 or 3)
    __shared__ _Float16 As[2][BM * 64];
    __shared__ _Float16 Bs[2][256 * 64];

    const int t    = threadIdx.x;
    const int lane = t & 63;
    const int wid  = t >> 6;            // 0..7
    const int wr   = wid >> 2;          // 0..1 (M)
    const int wc   = wid & 3;           // 0..3 (N)
    const int row0 = blockIdx.y * BM;
    const int col0 = blockIdx.x * 256;
    const int ln   = lane & 31;
    const int lh   = lane >> 5;

    f32x16 acc[MF][2];
#pragma unroll
    for (int i = 0; i < MF; ++i)
#pragma unroll
        for (int j = 0; j < 2; ++j)
#pragma unroll
            for (int r = 0; r < 16; ++r) acc[i][j][r] = 0.f;

    // Staging addresses (pre-swizzled global source, linear LDS dest).
    const _Float16* ap[MF]; int aoff[MF];
    const _Float16* bp[4];  int boff[4];
#pragma unroll
    for (int i = 0; i < MF; ++i) {
        int n = i * 512 + t, r = n >> 3, c = (n & 7) ^ (r & 7);
        ap[i]   = A + (size_t)(row0 + r) * K + c * 8;
        aoff[i] = (i * 512 + wid * 64) * 8;
    }
#pragma unroll
    for (int i = 0; i < 4; ++i) {
        int n = i * 512 + t, r = n >> 3, c = (n & 7) ^ (r & 7);
        bp[i]   = B + (size_t)(col0 + r) * K + c * 8;
        boff[i] = (i * 512 + wid * 64) * 8;
    }

    // Prologue: stage K-tile 0 into buffer 0 (MF+4 issues stay in flight).
#pragma unroll
    for (int i = 0; i < MF; ++i) { load_lds16(ap[i], &As[0][aoff[i]]); ap[i] += 64; }
#pragma unroll
    for (int i = 0; i < 4;  ++i) { load_lds16(bp[i], &Bs[0][boff[i]]); bp[i] += 64; }

    const int nt = K >> 6;
    for (int tt = 0; tt < nt; ++tt) {
        const int  cur = tt & 1, nxt = cur ^ 1;
        const bool hn  = (tt + 1 < nt);
        f16x8 bf[2][4];
#pragma unroll
        for (int p = 0; p < MF; ++p) {
            // Stage this phase's share of the NEXT K-tile.
            if (hn) {
                load_lds16(ap[p], &As[nxt][aoff[p]]); ap[p] += 64;
                if constexpr (SPP == 2) {
                    load_lds16(bp[p], &Bs[nxt][boff[p]]); bp[p] += 64;
                } else {
                    load_lds16(bp[2*p],   &Bs[nxt][boff[2*p]]);   bp[2*p]   += 64;
                    load_lds16(bp[2*p+1], &Bs[nxt][boff[2*p+1]]); bp[2*p+1] += 64;
                }
            }
            if (p == 0) {
                // Current buffer ready when our prev-tile loads drained;
                // the SPP just-issued loads stay in flight (T4).
                if (hn) asm volatile("s_waitcnt vmcnt(%0)" :: "i"(SPP) : "memory");
                else    asm volatile("s_waitcnt vmcnt(0)" ::: "memory");
                bar();
#pragma unroll
                for (int tj = 0; tj < 2; ++tj)
#pragma unroll
                    for (int ks = 0; ks < 4; ++ks) {
                        int n = wc * 64 + tj * 32 + ln;
                        int c = (ks * 2 + lh) ^ (n & 7);
                        bf[tj][ks] = *(const f16x8*)&Bs[cur][n * 64 + c * 8];
                    }
            }
            f16x8 af[4];
#pragma unroll
            for (int ks = 0; ks < 4; ++ks) {
                int r = wr * (BM / 2) + p * 32 + ln;
                int c = (ks * 2 + lh) ^ (r & 7);
                af[ks] = *(const f16x8*)&As[cur][r * 64 + c * 8];
            }
            __builtin_amdgcn_s_setprio(1);
#pragma unroll
            for (int ks = 0; ks < 4; ++ks)
#pragma unroll
                for (int tj = 0; tj < 2; ++tj)
                    acc[p][tj] = __builtin_amdgcn_mfma_f32_32x32x16_f16(
                        af[ks], bf[tj][ks], acc[p][tj], 0, 0, 0);
            __builtin_amdgcn_s_setprio(0);
            bar();
        }
    }

    // Epilogue. C/D layout (32x32): col = lane&31, row = (reg&3)+8*(reg>>2)+4*(lane>>5).
#pragma unroll
    for (int ti = 0; ti < MF; ++ti) {
#pragma unroll
        for (int tj = 0; tj < 2; ++tj) {
            const int gc = col0 + wc * 64 + tj * 32 + ln;
#pragma unroll
            for (int reg = 0; reg < 16; ++reg) {
                const int gr = row0 + wr * (BM / 2) + ti * 32
                             + (reg & 3) + 8 * (reg >> 2) + 4 * lh;
                const float v = acc[ti][tj][reg];
                if constexpr (EPI == 0) {
                    C16[(size_t)gr * N + gc] = (_Float16)v;
                } else if constexpr (EPI == 1) {
                    C16[(size_t)gr * N + gc] = (_Float16)fmaxf(v + bias[gc], 0.f);
                } else if constexpr (EPI == 4) {
                    const int half = N >> 1;
                    if (gc < half)
                        C16[(size_t)gr * half + gc] = (_Float16)(v + bias[gc]);
                    else
                        C2[(size_t)gr * half + (gc - half)] =
                            (_Float16)(v + bias2[gc - half]);
                }
            }
        }
    }
}

// ---------------------------------------------------------------------------
// Legacy 128x128 GEMM (R4 core) for small-N shapes (gemm2 N=2048, gemm7
// N=1024) where 256-wide tiles would idle half the chip.
// ---------------------------------------------------------------------------
template <int EPI>
__global__ __launch_bounds__(256, 3)
void gemm16(const _Float16* __restrict__ A, const _Float16* __restrict__ B,
            _Float16* __restrict__ C16, float* __restrict__ Cf,
            int M, int N, int K, int Nc,
            const float* __restrict__ bias)
{
    __shared__ _Float16 As[128 * 64];
    __shared__ _Float16 Bs[128 * 64];
    const int t    = threadIdx.x;
    const int lane = t & 63;
    const int wid  = t >> 6;            // 0..3
    const int wr   = wid >> 1;          // wave row 0..1
    const int wc   = wid & 1;           // wave col 0..1
    const int row0 = blockIdx.y * 128;
    const int col0 = blockIdx.x * 128;

    f32x16 acc[2][2];
#pragma unroll
    for (int i = 0; i < 2; ++i)
#pragma unroll
        for (int j = 0; j < 2; ++j)
#pragma unroll
            for (int r = 0; r < 16; ++r) acc[i][j][r] = 0.f;

    const _Float16* ap[4];
    const _Float16* bp[4];
    int loff[4];
#pragma unroll
    for (int i = 0; i < 4; ++i) {
        int n  = i * 256 + t;
        int r  = n >> 3;
        int c  = (n & 7) ^ (r & 7);
        ap[i]   = A + (size_t)(row0 + r) * K + c * 8;
        bp[i]   = B + (size_t)(col0 + r) * K + c * 8;
        loff[i] = (i * 256 + wid * 64) * 8;
    }

    const int ln = lane & 31;
    const int lh = lane >> 5;

    for (int k0 = 0; k0 < K; k0 += 64) {
#pragma unroll
        for (int i = 0; i < 4; ++i) {
            load_lds16(ap[i], &As[loff[i]]);
            load_lds16(bp[i], &Bs[loff[i]]);
            ap[i] += 64; bp[i] += 64;
        }
        __syncthreads();
#pragma unroll
        for (int ks = 0; ks < 4; ++ks) {
            f16x8 af[2], bf[2];
#pragma unroll
            for (int ti = 0; ti < 2; ++ti) {
                int r = wr * 64 + ti * 32 + ln;
                int c = (ks * 2 + lh) ^ (r & 7);
                af[ti] = *(const f16x8*)&As[r * 64 + c * 8];
            }
#pragma unroll
            for (int tj = 0; tj < 2; ++tj) {
                int n = wc * 64 + tj * 32 + ln;
                int c = (ks * 2 + lh) ^ (n & 7);
                bf[tj] = *(const f16x8*)&Bs[n * 64 + c * 8];
            }
#pragma unroll
            for (int ti = 0; ti < 2; ++ti)
#pragma unroll
                for (int tj = 0; tj < 2; ++tj)
                    acc[ti][tj] = __builtin_amdgcn_mfma_f32_32x32x16_f16(
                        af[ti], bf[tj], acc[ti][tj], 0, 0, 0);
        }
        __syncthreads();
    }

#pragma unroll
    for (int ti = 0; ti < 2; ++ti) {
#pragma unroll
        for (int tj = 0; tj < 2; ++tj) {
            const int gc = col0 + wc * 64 + tj * 32 + ln;
#pragma unroll
            for (int reg = 0; reg < 16; ++reg) {
                const int gr = row0 + wr * 64 + ti * 32
                             + (reg & 3) + 8 * (reg >> 2) + 4 * lh;
                const float v = acc[ti][tj][reg];
                if constexpr (EPI == 0) {
                    C16[(size_t)gr * N + gc] = (_Float16)v;
                } else if constexpr (EPI == 1) {
                    C16[(size_t)gr * N + gc] = (_Float16)fmaxf(v + bias[gc], 0.f);
                } else if constexpr (EPI == 3) {
                    C16[(size_t)gr * N + gc] = (_Float16)(v + bias[gc]);
                } else if constexpr (EPI == 7) {
                    if (gc < Nc) Cf[(size_t)gr * Nc + gc] = v + bias[gc];
                }
            }
        }
    }
}

extern "C" void kernel_launch(void* const* d_in, const int* in_sizes, int n_in,
                              void* d_out, int out_size, void* d_ws, size_t ws_size,
                              hipStream_t stream)
{
    (void)in_sizes; (void)n_in; (void)out_size; (void)ws_size;

    const float* x      = (const float*)d_in[0];
    const int*   mm     = (const int*)  d_in[1];
    const float* priors = (const float*)d_in[2];
    const float* W1  = (const float*)d_in[3];
    const float* b1  = (const float*)d_in[4];
    const float* W2  = (const float*)d_in[5];
    const float* b2  = (const float*)d_in[6];
    const float* Wr1 = (const float*)d_in[7];
    const float* br1 = (const float*)d_in[8];
    const float* Wlv = (const float*)d_in[9];
    const float* blv = (const float*)d_in[10];
    const float* Wg1 = (const float*)d_in[11];
    const float* bg1 = (const float*)d_in[12];
    const float* Wm  = (const float*)d_in[13];
    const float* bm  = (const float*)d_in[14];
    const float* Wl  = (const float*)d_in[15];
    const float* bl  = (const float*)d_in[16];
    const float* eps_w = (const float*)d_in[17];
    const float* eps_r = (const float*)d_in[18];

    float* out        = (float*)d_out;
    float* out_logits = out;                           // 4096x1000
    float* out_w      = out + (size_t)4096 * 1000;     // 2048x2048
    float* out_var    = out_w + (size_t)2048 * 2048;   // 2048x2048

    // Workspace layout (~288 MB):
    int* perm = (int*)d_ws;
    char* base = (char*)d_ws + 32768;
    _Float16* wr1h  = (_Float16*)(base);                    // 32 MB
    _Float16* wlvh  = (_Float16*)(base + 33554432);         // 16 MB
    _Float16* priTh = (_Float16*)(base + 50331648);         // 16 MB [4096,2048]
    _Float16* wg1h  = (_Float16*)(base + 67108864);         // 32 MB
    _Float16* wmh   = (_Float16*)(base + 100663296);        // 32 MB  [Wm;Wl] = 8192x4096
    _Float16* wlh   = (_Float16*)(base + 134217728);        // 32 MB  (contiguous after wmh)
    _Float16* w1h   = (_Float16*)(base + 167772160);        // 32 MB
    _Float16* w2ph  = (_Float16*)(base + 201326592);        // 8 MB [1024,4096]
    char* acts = base + 209715200;
    _Float16* xm16   = (_Float16*)(acts);                   // 16 MB (xrec16 alias)
    _Float16* h16    = (_Float16*)(acts + 16777216);        // 16 MB (hr16 alias)
    _Float16* w16    = (_Float16*)(acts + 33554432);        //  8 MB
    _Float16* mtmp16 = (_Float16*)(acts + 41943040);        // 16 MB (lvf alias)
    _Float16* comb16 = (_Float16*)(acts + 58720256);        // 32 MB
    _Float16* xrec16 = xm16;    // x_m dead after gemm1
    _Float16* hr16   = h16;     // h dead after gemm2
    _Float16* h1_16  = xm16;    // branch dead after ew_reg (32 MB over xm16+h16)
    float*    lvf    = (float*)mtmp16;                      // fp32 [2048,2048] = 16 MB,
                                                            // dead before gemm5 writes mtmp16
    _Float16* comb_bot = comb16 + (size_t)2048 * 4096;

    perm_kernel<<<1, 1024, 0, stream>>>(mm, perm);

    // Weight conversions (fp32 -> fp16).
    cvt_all_kernel<<<90112, 256, 0, stream>>>(Wr1, Wlv, Wg1, Wm, Wl, W1,
                                              wr1h, wlvh, wg1h, wmh, wlh, w1h);
    cvt_t_kernel<<<dim3(128, 64), dim3(32, 8), 0, stream>>>(priors, priTh);
    cvt_w2_kernel<<<4096, 256, 0, stream>>>(W2, w2ph);

    gather_kernel<<<dim3(4, 4096), 256, 0, stream>>>(x, perm, comb16, xm16);

    // 1: h = relu(x_m @ Wr1^T + br1)          [2048,4096] K=4096
    gemm8p<128, 1><<<dim3(16, 16), 512, 0, stream>>>(
        xm16, wr1h, h16, nullptr, 4096, 4096, br1, nullptr);
    // 2: logvar = h @ Wlv^T + blv -> fp32     [2048,2048] K=4096 (legacy core)
    gemm16<7><<<dim3(16, 16), 256, 0, stream>>>(
        h16, wlvh, nullptr, lvf, 2048, 2048, 4096, 2048, blv);
    // 2b: w/var elementwise (streaming)
    ew_w_kernel<<<2048, 256, 0, stream>>>(lvf, eps_w, perm, w16, out_w, out_var);
    // 3: x_rec = w @ priors                    [2048,4096] K=2048
    gemm8p<128, 0><<<dim3(16, 16), 512, 0, stream>>>(
        w16, priTh, xrec16, nullptr, 4096, 2048, nullptr, nullptr);
    // 4: hr = relu(x_rec @ Wg1^T + bg1)        [2048,4096] K=4096
    gemm8p<128, 1><<<dim3(16, 16), 512, 0, stream>>>(
        xrec16, wg1h, hr16, nullptr, 4096, 4096, bg1, nullptr);
    // 5: [mean_reg | lr] = hr @ [Wm;Wl]^T      [2048,8192] K=4096 (fused 5a+5b)
    gemm8p<128, 4><<<dim3(32, 16), 512, 0, stream>>>(
        hr16, wmh, mtmp16, comb_bot, 8192, 4096, bm, bl);
    // 5c: x_reg = x_rec * softplus(mean + exp(0.5*lr)*eps_r) (in place, streaming)
    ew_reg_kernel<<<2048, 512, 0, stream>>>(comb_bot, mtmp16, xrec16, eps_r, perm);
    // 6: h1 = relu(comb @ W1^T + b1)           [4096,4096] K=4096
    gemm8p<256, 1><<<dim3(16, 16), 512, 0, stream>>>(
        comb16, w1h, h1_16, nullptr, 4096, 4096, b1, nullptr);
    // 7: logits = h1 @ W2^T + b2 (fp32 out, guard gc<1000, legacy core)
    gemm16<7><<<dim3(8, 32), 256, 0, stream>>>(
        h1_16, w2ph, nullptr, out_logits, 4096, 1024, 4096, 1000, b2);
}